// Round 14
// baseline (304.310 us; speedup 1.0000x reference)
//
#include <hip/hip_runtime.h>
#include <hip/hip_bf16.h>

#define B_      16
#define C_      256
#define H_      56
#define W_      56
#define HW_     3136
#define G_      64
#define P_      49
#define NTOK    50176
#define HEADS_  8
#define DH_     32
#define SCALE_  0.0625f
#define EPS_    1e-5f

typedef short bf16x8 __attribute__((ext_vector_type(8)));
typedef short bf16x4_t __attribute__((ext_vector_type(4)));
typedef float f32x4  __attribute__((ext_vector_type(4)));
using bf16 = __hip_bfloat16;

__device__ __forceinline__ void gload16(const void* g, void* l) {
  __builtin_amdgcn_global_load_lds((const __attribute__((address_space(1))) void*)g,
                                   (__attribute__((address_space(3))) void*)l, 16, 0, 0);
}
__device__ __forceinline__ float b2f(short s) {
  union { float f; unsigned u; } v; v.u = ((unsigned)(unsigned short)s) << 16; return v.f;
}
__device__ __forceinline__ short f2b(float f) {   // RNE
  union { float f; unsigned u; } v; v.f = f;
  unsigned r = (v.u + 0x7FFFu + ((v.u >> 16) & 1u)) >> 16;
  return (short)r;
}

// ---------------------------------------------------------------------------
// prep: weights -> [N][K] bf16; bias -> bt[h][key(64)][q*4+qni] bf16
// ---------------------------------------------------------------------------
__global__ __launch_bounds__(256)
void prep_kernel(const float* __restrict__ wqkv, const float* __restrict__ wmerge,
                 const float* __restrict__ w1, const float* __restrict__ w2,
                 const float* __restrict__ btab, const int* __restrict__ relidx,
                 bf16* __restrict__ wqkvT, bf16* __restrict__ wmergeT,
                 bf16* __restrict__ w1T, bf16* __restrict__ w2T,
                 short* __restrict__ bt)
{
  int idx = blockIdx.x * 256 + threadIdx.x;
  if (idx < 196608) { int n = idx >> 8, k = idx & 255;
    wqkvT[idx] = __float2bfloat16(wqkv[k * 768 + n]); return; }
  idx -= 196608;
  if (idx < 65536) { int n = idx >> 8, k = idx & 255;
    wmergeT[idx] = __float2bfloat16(wmerge[k * 256 + n]); return; }
  idx -= 65536;
  if (idx < 262144) { int n = idx >> 8, k = idx & 255;
    w1T[idx] = __float2bfloat16(w1[k * 1024 + n]); return; }
  idx -= 262144;
  if (idx < 262144) { int n = idx >> 10, k = idx & 1023;
    w2T[idx] = __float2bfloat16(w2[k * 256 + n]); return; }
  idx -= 262144;
  if (idx < 32768) {
    int h = idx >> 12, rest = idx & 4095;
    int key = rest >> 6, col = rest & 63;
    int q = col >> 2, qni = col & 3;
    int query = qni * 16 + q;
    float v = 0.f;
    if (key < P_ && query < P_) v = btab[relidx[query * P_ + key] * HEADS_ + h];
    bt[idx] = f2b(v);
  }
}

// ---------------------------------------------------------------------------
// ingest: coalesced BCHW float4 read -> LDS transpose -> LN1 -> xtok + y
// ---------------------------------------------------------------------------
__global__ __launch_bounds__(256)
void ingest_kernel(const float* __restrict__ x, const float* __restrict__ gam,
                   const float* __restrict__ bet, short* __restrict__ xtok,
                   short* __restrict__ y)
{
  __shared__ short Lt[56 * 260];
  const int h = blockIdx.x % 56, b = blockIdx.x / 56;
  const int tid = threadIdx.x;

  const float* xb = x + (size_t)b * 256 * HW_ + h * 56;
#pragma unroll
  for (int i = 0; i < 14; i++) {
    int idx = i * 256 + tid;
    int c = idx / 14, w4 = idx - c * 14;
    float4 v = *(const float4*)(xb + (size_t)c * HW_ + w4 * 4);
    Lt[(w4 * 4 + 0) * 260 + c] = f2b(v.x);
    Lt[(w4 * 4 + 1) * 260 + c] = f2b(v.y);
    Lt[(w4 * 4 + 2) * 260 + c] = f2b(v.z);
    Lt[(w4 * 4 + 3) * 260 + c] = f2b(v.w);
  }
  __syncthreads();

  const int lane = tid & 63, wv = tid >> 6;
  float4 gv = *(const float4*)(gam + lane * 4);
  float4 bv = *(const float4*)(bet + lane * 4);
  const int hdiv = h / 7, hmod = h - hdiv * 7;

  for (int t = 0; t < 14; t++) {
    int w = wv * 14 + t;
    bf16x4_t raw = *(const bf16x4_t*)&Lt[w * 260 + lane * 4];
    float f0 = b2f(raw[0]), f1 = b2f(raw[1]), f2 = b2f(raw[2]), f3 = b2f(raw[3]);
    float sum = f0 + f1 + f2 + f3;
    float sq  = f0*f0 + f1*f1 + f2*f2 + f3*f3;
#pragma unroll
    for (int off = 32; off > 0; off >>= 1) {
      sum += __shfl_xor(sum, off, 64);
      sq  += __shfl_xor(sq,  off, 64);
    }
    float mu = sum * (1.0f / 256.0f);
    float var = sq * (1.0f / 256.0f) - mu * mu;
    float rs = rsqrtf(var + EPS_);
    int wdiv = w / 7, wmod = w - wdiv * 7;
    int tok = b * HW_ + (hdiv * 8 + wdiv) * P_ + hmod * 7 + wmod;
    *(bf16x4_t*)(xtok + (size_t)tok * 256 + lane * 4) = raw;
    bf16x4_t o;
    o[0] = f2b((f0 - mu) * rs * gv.x + bv.x);
    o[1] = f2b((f1 - mu) * rs * gv.y + bv.y);
    o[2] = f2b((f2 - mu) * rs * gv.z + bv.z);
    o[3] = f2b((f3 - mu) * rs * gv.w + bv.w);
    *(bf16x4_t*)(y + (size_t)tok * 256 + lane * 4) = o;
  }
}

// ---------------------------------------------------------------------------
// ln2: xw (bf16 token-major) -> z bf16. wave per token.
// ---------------------------------------------------------------------------
__global__ __launch_bounds__(256)
void ln2_kernel(const short* __restrict__ xw, const float* __restrict__ gam,
                const float* __restrict__ bet, short* __restrict__ z)
{
  const int t = blockIdx.x * 4 + (threadIdx.x >> 6);
  const int lane = threadIdx.x & 63;
  bf16x4_t raw = *(const bf16x4_t*)(xw + (size_t)t * 256 + lane * 4);
  float v[4];
#pragma unroll
  for (int j = 0; j < 4; j++) v[j] = b2f(raw[j]);
  float sum = v[0] + v[1] + v[2] + v[3];
  float sq  = v[0]*v[0] + v[1]*v[1] + v[2]*v[2] + v[3]*v[3];
#pragma unroll
  for (int off = 32; off > 0; off >>= 1) {
    sum += __shfl_xor(sum, off, 64);
    sq  += __shfl_xor(sq,  off, 64);
  }
  float mu = sum * (1.0f / 256.0f);
  float var = sq * (1.0f / 256.0f) - mu * mu;
  float rs = rsqrtf(var + EPS_);
  bf16x4_t o;
#pragma unroll
  for (int j = 0; j < 4; j++) {
    int c = lane * 4 + j;
    o[j] = f2b((v[j] - mu) * rs * gam[c] + bet[c]);
  }
  *(bf16x4_t*)(z + (size_t)t * 256 + lane * 4) = o;
}

// ---------------------------------------------------------------------------
// egress: token-major bf16 -> BCHW f32 out
// ---------------------------------------------------------------------------
__global__ __launch_bounds__(256)
void egress_kernel(const short* __restrict__ outtok, float* __restrict__ out)
{
  const int h = blockIdx.x % 56, b = blockIdx.x / 56;
  const int w = threadIdx.x & 63, cblk = threadIdx.x >> 6;
  const bool act = w < 56;
  const int wcl = act ? w : 55;
  const int tok = b * HW_ + ((h / 7) * 8 + wcl / 7) * P_ + (h % 7) * 7 + (wcl % 7);
  const short* src = outtok + (size_t)tok * 256 + cblk * 64;
  float* dst = out + ((size_t)b * 256 + cblk * 64) * HW_ + h * 56 + w;
#pragma unroll
  for (int j0 = 0; j0 < 64; j0 += 8) {
    bf16x8 r = *(const bf16x8*)(src + j0);
#pragma unroll
    for (int jj = 0; jj < 8; jj++)
      if (act) dst[(size_t)(j0 + jj) * HW_] = b2f(r[jj]);
  }
}

// ---------------------------------------------------------------------------
// attention (MFMA): one wave per (window, head)
// ---------------------------------------------------------------------------
__global__ __launch_bounds__(64)
void attn_kernel(const short* __restrict__ qkv, const short* __restrict__ bt,
                 short* __restrict__ out)
{
  __shared__ short Pbuf[64 * 72];
  const int bid = blockIdx.x;
  const int h = bid & 7;
  const int t0 = (bid >> 3) * P_;
  const int lane = threadIdx.x;
  const int g = lane >> 4, q = lane & 15;

  const short* qb = qkv + (size_t)t0 * 768 + h * 32;

  bf16x8 vf[2][2];
#pragma unroll
  for (int kkt = 0; kkt < 2; kkt++)
#pragma unroll
    for (int n2 = 0; n2 < 2; n2++)
#pragma unroll
      for (int jj = 0; jj < 8; jj++) {
        int key = kkt * 32 + 8 * g + jj; key = key > 48 ? 48 : key;
        vf[kkt][n2][jj] = qb[(size_t)key * 768 + 512 + n2 * 16 + q];
      }

  bf16x8 kf[4], qf[4];
#pragma unroll
  for (int mi = 0; mi < 4; mi++) {
    int r_ = mi * 16 + q; r_ = r_ > 48 ? 48 : r_;
    kf[mi] = *(const bf16x8*)(qb + (size_t)r_ * 768 + 256 + 8 * g);
  }
#pragma unroll
  for (int ni = 0; ni < 4; ni++) {
    int r_ = ni * 16 + q; r_ = r_ > 48 ? 48 : r_;
    qf[ni] = *(const bf16x8*)(qb + (size_t)r_ * 768 + 8 * g);
  }

  f32x4 sacc[4][4] = {};
#pragma unroll
  for (int mi = 0; mi < 4; mi++)
#pragma unroll
    for (int ni = 0; ni < 4; ni++)
      sacc[mi][ni] = __builtin_amdgcn_mfma_f32_16x16x32_bf16(kf[mi], qf[ni], sacc[mi][ni], 0, 0, 0);

  float mx[4] = {-1e30f, -1e30f, -1e30f, -1e30f};
  const short* btb = bt + (size_t)(h * 64) * 64 + q * 4;
#pragma unroll
  for (int mi = 0; mi < 4; mi++)
#pragma unroll
    for (int r = 0; r < 4; r++) {
      int key = mi * 16 + 4 * g + r;
      bf16x4_t bv = *(const bf16x4_t*)(btb + key * 64);
      bool valid = key < P_;
#pragma unroll
      for (int ni = 0; ni < 4; ni++) {
        float s = valid ? fmaf(sacc[mi][ni][r], SCALE_, b2f(bv[ni])) : -1e30f;
        sacc[mi][ni][r] = s;
        mx[ni] = fmaxf(mx[ni], s);
      }
    }
#pragma unroll
  for (int ni = 0; ni < 4; ni++) {
    mx[ni] = fmaxf(mx[ni], __shfl_xor(mx[ni], 16, 64));
    mx[ni] = fmaxf(mx[ni], __shfl_xor(mx[ni], 32, 64));
  }
  float sm[4] = {0.f, 0.f, 0.f, 0.f};
#pragma unroll
  for (int mi = 0; mi < 4; mi++)
#pragma unroll
    for (int ni = 0; ni < 4; ni++)
#pragma unroll
      for (int r = 0; r < 4; r++) {
        float p = __expf(sacc[mi][ni][r] - mx[ni]);
        sacc[mi][ni][r] = p;
        sm[ni] += p;
      }
#pragma unroll
  for (int ni = 0; ni < 4; ni++) {
    sm[ni] += __shfl_xor(sm[ni], 16, 64);
    sm[ni] += __shfl_xor(sm[ni], 32, 64);
    sm[ni] = 1.0f / sm[ni];
  }
#pragma unroll
  for (int ni = 0; ni < 4; ni++)
#pragma unroll
    for (int mi = 0; mi < 4; mi++) {
      bf16x4_t pv;
#pragma unroll
      for (int r = 0; r < 4; r++) pv[r] = f2b(sacc[mi][ni][r] * sm[ni]);
      *(bf16x4_t*)&Pbuf[(ni * 16 + q) * 72 + mi * 16 + 4 * g] = pv;
    }
  __syncthreads();

  f32x4 oacc[4][2] = {};
#pragma unroll
  for (int kkt = 0; kkt < 2; kkt++) {
    bf16x8 paf[4];
#pragma unroll
    for (int qi = 0; qi < 4; qi++)
      paf[qi] = *(const bf16x8*)&Pbuf[(qi * 16 + q) * 72 + kkt * 32 + 8 * g];
#pragma unroll
    for (int qi = 0; qi < 4; qi++)
#pragma unroll
      for (int n2 = 0; n2 < 2; n2++)
        oacc[qi][n2] = __builtin_amdgcn_mfma_f32_16x16x32_bf16(paf[qi], vf[kkt][n2], oacc[qi][n2], 0, 0, 0);
  }

  short* ob = out + (size_t)t0 * 256 + h * 32;
#pragma unroll
  for (int qi = 0; qi < 4; qi++)
#pragma unroll
    for (int r = 0; r < 4; r++) {
      int query = qi * 16 + 4 * g + r;
      if (query < P_) {
#pragma unroll
        for (int n2 = 0; n2 < 2; n2++)
          ob[(size_t)query * 256 + n2 * 16 + q] = f2b(oacc[qi][n2][r]);
      }
    }
}

// ---------------------------------------------------------------------------
// GEMM <EPI, WR, WC, NI>: waves WRxWC, wave-tile 64 x NI*16, BM=WR*64,
// BN=WC*NI*16, threads=WR*WC*64. Depth-2 LDS pipeline (R11 structure):
// raw s_barrier + counted s_waitcnt vmcnt(4). T2 source swizzle + swizzled
// ds_read. Big variant <_,4,2,8>: 32 MFMA between barriers (2x R11).
// EPI 0: bf16 store   EPI 1: gelu(erff) -> bf16   EPI 2: in-place residual add
// ---------------------------------------------------------------------------
template<int EPI, int WR, int WC, int NI>
__global__ __launch_bounds__(WR * WC * 64)
void gemm_kernel(const bf16* __restrict__ A, const bf16* __restrict__ Wt,
                 const float* __restrict__ bias, int N, int K,
                 bf16* __restrict__ outb, short* __restrict__ res_io)
{
  constexpr int THREADS = WR * WC * 64;
  constexpr int BM = WR * 64;
  constexpr int BN = WC * NI * 16;
  constexpr int RPP = THREADS / 4;      // rows staged per pass
  constexpr int APASS = BM / RPP;       // 2 for both variants
  constexpr int BPASS = BN / RPP;       // 2 for both variants
  __shared__ __align__(16) bf16 As[2][BM * 32];
  __shared__ __align__(16) bf16 Bs[2][BN * 32];

  const int tid = threadIdx.x;
  const int lane = tid & 63;
  const int wave = tid >> 6;
  const int wr = wave / WC, wc = wave % WC;
  const int bm = blockIdx.y * BM, bn = blockIdx.x * BN;

  f32x4 acc[4][NI] = {};

  const int trow = tid >> 2;
  const int tcol = ((tid & 3) ^ ((tid >> 3) & 3)) * 8;   // swizzled source chunk
  const bf16* aA[APASS];
#pragma unroll
  for (int p = 0; p < APASS; p++)
    aA[p] = A + (size_t)(bm + p * RPP + trow) * K + tcol;
  const bf16* aB[BPASS];
#pragma unroll
  for (int p = 0; p < BPASS; p++)
    aB[p] = Wt + (size_t)(bn + p * RPP + trow) * K + tcol;
  const int dOff = tid * 8;

  const int kc_sw = ((lane >> 4) ^ ((lane >> 1) & 3)) * 8;  // swizzled read chunk
  const int l15 = lane & 15, g = lane >> 4;
  const int rA = wr * 64 + l15;
  const int rB = wc * (NI * 16) + l15;

  const int nt = K >> 5;

  // prologue: stage tiles 0 and 1
#pragma unroll
  for (int p = 0; p < APASS; p++) gload16(aA[p], &As[0][p * RPP * 32 + dOff]);
#pragma unroll
  for (int p = 0; p < BPASS; p++) gload16(aB[p], &Bs[0][p * RPP * 32 + dOff]);
#pragma unroll
  for (int p = 0; p < APASS; p++) gload16(aA[p] + 32, &As[1][p * RPP * 32 + dOff]);
#pragma unroll
  for (int p = 0; p < BPASS; p++) gload16(aB[p] + 32, &Bs[1][p * RPP * 32 + dOff]);

  for (int t = 0; t < nt; ++t) {
    const int cur = t & 1;
    // wait for THIS tile's stage only; next tile's 4 loads stay in flight
    if (t + 1 < nt) asm volatile("s_waitcnt vmcnt(4)" ::: "memory");
    else            asm volatile("s_waitcnt vmcnt(0)" ::: "memory");
    __builtin_amdgcn_s_barrier();          // tile t visible to all waves

    bf16x8 af[4], bfr[NI];
#pragma unroll
    for (int i = 0; i < 4; i++)
      af[i]  = *(const bf16x8*)(&As[cur][(rA + i * 16) * 32 + kc_sw]);
#pragma unroll
    for (int i = 0; i < NI; i++)
      bfr[i] = *(const bf16x8*)(&Bs[cur][(rB + i * 16) * 32 + kc_sw]);
#pragma unroll
    for (int mi = 0; mi < 4; mi++)
#pragma unroll
      for (int ni = 0; ni < NI; ni++)
        acc[mi][ni] = __builtin_amdgcn_mfma_f32_16x16x32_bf16(af[mi], bfr[ni], acc[mi][ni], 0, 0, 0);

    __builtin_amdgcn_s_barrier();          // all waves done reading buf[cur]
    if (t + 2 < nt) {                      // refill the freed buffer
      const int k2 = (t + 2) << 5;
#pragma unroll
      for (int p = 0; p < APASS; p++) gload16(aA[p] + k2, &As[cur][p * RPP * 32 + dOff]);
#pragma unroll
      for (int p = 0; p < BPASS; p++) gload16(aB[p] + k2, &Bs[cur][p * RPP * 32 + dOff]);
    }
  }

#pragma unroll
  for (int mi = 0; mi < 4; mi++) {
#pragma unroll
    for (int ni = 0; ni < NI; ni++) {
      const int col = bn + wc * (NI * 16) + ni * 16 + l15;
      const float bv = bias[col];
#pragma unroll
      for (int r = 0; r < 4; r++) {
        const int row = bm + wr * 64 + mi * 16 + g * 4 + r;
        float v = acc[mi][ni][r] + bv;
        if (EPI == 0) {
          outb[(size_t)row * N + col] = __float2bfloat16(v);
        } else if (EPI == 1) {
          float gv = 0.5f * v * (1.0f + erff(v * 0.70710678118f));
          outb[(size_t)row * N + col] = __float2bfloat16(gv);
        } else {
          size_t o = (size_t)row * 256 + col;
          res_io[o] = f2b(v + b2f(res_io[o]));
        }
      }
    }
  }
}

// ---------------------------------------------------------------------------
extern "C" void kernel_launch(void* const* d_in, const int* in_sizes, int n_in,
                              void* d_out, int out_size, void* d_ws, size_t ws_size,
                              hipStream_t stream)
{
  const float* x      = (const float*)d_in[0];
  const float* ln1_g  = (const float*)d_in[1];
  const float* ln1_b  = (const float*)d_in[2];
  const float* wqkv   = (const float*)d_in[3];
  const float* bqkv   = (const float*)d_in[4];
  const float* wmerge = (const float*)d_in[5];
  const float* bmerge = (const float*)d_in[6];
  const float* btab   = (const float*)d_in[7];
  const float* ln2_g  = (const float*)d_in[8];
  const float* ln2_b  = (const float*)d_in[9];
  const float* w1     = (const float*)d_in[10];
  const float* b1     = (const float*)d_in[11];
  const float* w2     = (const float*)d_in[12];
  const float* b2     = (const float*)d_in[13];
  const int*   relidx = (const int*)d_in[14];
  float* out = (float*)d_out;

  char* ws = (char*)d_ws;
  bf16*  wqkvT   = (bf16*)(ws);                   // 393,216
  bf16*  wmergeT = (bf16*)(ws + 393216);          // 131,072
  bf16*  w1T     = (bf16*)(ws + 524288);          // 524,288
  bf16*  w2T     = (bf16*)(ws + 1048576);         // 524,288
  short* battn   = (short*)(ws + 1572864);        // 65,536
  short* R1      = (short*)(ws + 1638400);        // 25,690,112 residual stream
  short* R2      = (short*)(ws + 27328512);       // 25,690,112 y -> z
  // chunked region at 53,018,624:
  //   nchunk=2: qkvc 38.5MB + attnc 12.8MB (R11 layout, 104.4MB total - known fit)
  //   nchunk=1: qkvc 77.1MB + attnc 25.7MB (155.8MB total - only if ws allows)
  const size_t CH1_NEED = 53018624ull + (size_t)NTOK * 1024 * 2 + (size_t)NTOK * 256 * 2;
  const int nchunk = (ws_size >= CH1_NEED) ? 1 : 2;
  const int ctok = NTOK / nchunk;
  short* qkvc  = (short*)(ws + 53018624);
  short* attnc = qkvc + (size_t)ctok * 768;
  short* hbuf  = qkvc;                            // aliases qkvc+attnc (dead by MLP)

  prep_kernel<<<3200, 256, 0, stream>>>(wqkv, wmerge, w1, w2, btab, relidx,
                                        wqkvT, wmergeT, w1T, w2T, battn);

  ingest_kernel<<<896, 256, 0, stream>>>(x, ln1_g, ln1_b, R1, R2);

  // attention path, nchunk window-aligned chunks
  for (int c = 0; c < nchunk; ++c) {
    size_t r0 = (size_t)c * ctok;
    gemm_kernel<0, 4, 2, 8><<<dim3(3, ctok / 256), 512, 0, stream>>>(
        (const bf16*)(R2 + r0 * 256), wqkvT, bqkv, 768, 256, (bf16*)qkvc, nullptr);
    attn_kernel<<<(ctok / P_) * 8, 64, 0, stream>>>(qkvc, battn, attnc);
    gemm_kernel<2, 2, 2, 4><<<dim3(2, ctok / 128), 256, 0, stream>>>(
        (const bf16*)attnc, wmergeT, bmerge, 256, 256, nullptr, R1 + r0 * 256);
  }

  // LN2 over full xw -> z
  ln2_kernel<<<NTOK / 4, 256, 0, stream>>>(R1, ln2_g, ln2_b, R2);

  // MLP, nchunk chunks
  for (int c = 0; c < nchunk; ++c) {
    size_t r0 = (size_t)c * ctok;
    gemm_kernel<1, 4, 2, 8><<<dim3(4, ctok / 256), 512, 0, stream>>>(
        (const bf16*)(R2 + r0 * 256), w1T, b1, 1024, 256, (bf16*)hbuf, nullptr);
    gemm_kernel<2, 2, 2, 4><<<dim3(2, ctok / 128), 256, 0, stream>>>(
        (const bf16*)hbuf, w2T, b2, 256, 1024, nullptr, R1 + r0 * 256);
  }

  egress_kernel<<<896, 256, 0, stream>>>(R1, out);
}

// Round 15
// 266.531 us; speedup vs baseline: 1.1417x; 1.1417x over previous
//
#include <hip/hip_runtime.h>
#include <hip/hip_bf16.h>

#define B_      16
#define C_      256
#define H_      56
#define W_      56
#define HW_     3136
#define G_      64
#define P_      49
#define NTOK    50176
#define HEADS_  8
#define DH_     32
#define SCALE_  0.0625f
#define EPS_    1e-5f

typedef short bf16x8 __attribute__((ext_vector_type(8)));
typedef short bf16x4_t __attribute__((ext_vector_type(4)));
typedef float f32x4  __attribute__((ext_vector_type(4)));
using bf16 = __hip_bfloat16;

__device__ __forceinline__ void gload16(const void* g, void* l) {
  __builtin_amdgcn_global_load_lds((const __attribute__((address_space(1))) void*)g,
                                   (__attribute__((address_space(3))) void*)l, 16, 0, 0);
}
__device__ __forceinline__ float b2f(short s) {
  union { float f; unsigned u; } v; v.u = ((unsigned)(unsigned short)s) << 16; return v.f;
}
__device__ __forceinline__ short f2b(float f) {   // RNE
  union { float f; unsigned u; } v; v.f = f;
  unsigned r = (v.u + 0x7FFFu + ((v.u >> 16) & 1u)) >> 16;
  return (short)r;
}

// ---------------------------------------------------------------------------
// prep: weights -> [N][K] bf16; bias -> bt[h][key(64)][q*4+qni] bf16
// ---------------------------------------------------------------------------
__global__ __launch_bounds__(256)
void prep_kernel(const float* __restrict__ wqkv, const float* __restrict__ wmerge,
                 const float* __restrict__ w1, const float* __restrict__ w2,
                 const float* __restrict__ btab, const int* __restrict__ relidx,
                 bf16* __restrict__ wqkvT, bf16* __restrict__ wmergeT,
                 bf16* __restrict__ w1T, bf16* __restrict__ w2T,
                 short* __restrict__ bt)
{
  int idx = blockIdx.x * 256 + threadIdx.x;
  if (idx < 196608) { int n = idx >> 8, k = idx & 255;
    wqkvT[idx] = __float2bfloat16(wqkv[k * 768 + n]); return; }
  idx -= 196608;
  if (idx < 65536) { int n = idx >> 8, k = idx & 255;
    wmergeT[idx] = __float2bfloat16(wmerge[k * 256 + n]); return; }
  idx -= 65536;
  if (idx < 262144) { int n = idx >> 8, k = idx & 255;
    w1T[idx] = __float2bfloat16(w1[k * 1024 + n]); return; }
  idx -= 262144;
  if (idx < 262144) { int n = idx >> 10, k = idx & 1023;
    w2T[idx] = __float2bfloat16(w2[k * 256 + n]); return; }
  idx -= 262144;
  if (idx < 32768) {
    int h = idx >> 12, rest = idx & 4095;
    int key = rest >> 6, col = rest & 63;
    int q = col >> 2, qni = col & 3;
    int query = qni * 16 + q;
    float v = 0.f;
    if (key < P_ && query < P_) v = btab[relidx[query * P_ + key] * HEADS_ + h];
    bt[idx] = f2b(v);
  }
}

// ---------------------------------------------------------------------------
// ingest: coalesced BCHW float4 read -> LDS transpose -> LN1 -> xtok + y
// ---------------------------------------------------------------------------
__global__ __launch_bounds__(256)
void ingest_kernel(const float* __restrict__ x, const float* __restrict__ gam,
                   const float* __restrict__ bet, short* __restrict__ xtok,
                   short* __restrict__ y)
{
  __shared__ short Lt[56 * 260];
  const int h = blockIdx.x % 56, b = blockIdx.x / 56;
  const int tid = threadIdx.x;

  const float* xb = x + (size_t)b * 256 * HW_ + h * 56;
#pragma unroll
  for (int i = 0; i < 14; i++) {
    int idx = i * 256 + tid;
    int c = idx / 14, w4 = idx - c * 14;
    float4 v = *(const float4*)(xb + (size_t)c * HW_ + w4 * 4);
    Lt[(w4 * 4 + 0) * 260 + c] = f2b(v.x);
    Lt[(w4 * 4 + 1) * 260 + c] = f2b(v.y);
    Lt[(w4 * 4 + 2) * 260 + c] = f2b(v.z);
    Lt[(w4 * 4 + 3) * 260 + c] = f2b(v.w);
  }
  __syncthreads();

  const int lane = tid & 63, wv = tid >> 6;
  float4 gv = *(const float4*)(gam + lane * 4);
  float4 bv = *(const float4*)(bet + lane * 4);
  const int hdiv = h / 7, hmod = h - hdiv * 7;

  for (int t = 0; t < 14; t++) {
    int w = wv * 14 + t;
    bf16x4_t raw = *(const bf16x4_t*)&Lt[w * 260 + lane * 4];
    float f0 = b2f(raw[0]), f1 = b2f(raw[1]), f2 = b2f(raw[2]), f3 = b2f(raw[3]);
    float sum = f0 + f1 + f2 + f3;
    float sq  = f0*f0 + f1*f1 + f2*f2 + f3*f3;
#pragma unroll
    for (int off = 32; off > 0; off >>= 1) {
      sum += __shfl_xor(sum, off, 64);
      sq  += __shfl_xor(sq,  off, 64);
    }
    float mu = sum * (1.0f / 256.0f);
    float var = sq * (1.0f / 256.0f) - mu * mu;
    float rs = rsqrtf(var + EPS_);
    int wdiv = w / 7, wmod = w - wdiv * 7;
    int tok = b * HW_ + (hdiv * 8 + wdiv) * P_ + hmod * 7 + wmod;
    *(bf16x4_t*)(xtok + (size_t)tok * 256 + lane * 4) = raw;
    bf16x4_t o;
    o[0] = f2b((f0 - mu) * rs * gv.x + bv.x);
    o[1] = f2b((f1 - mu) * rs * gv.y + bv.y);
    o[2] = f2b((f2 - mu) * rs * gv.z + bv.z);
    o[3] = f2b((f3 - mu) * rs * gv.w + bv.w);
    *(bf16x4_t*)(y + (size_t)tok * 256 + lane * 4) = o;
  }
}

// ---------------------------------------------------------------------------
// ln2: xw (bf16 token-major) -> z bf16. wave per token.
// ---------------------------------------------------------------------------
__global__ __launch_bounds__(256)
void ln2_kernel(const short* __restrict__ xw, const float* __restrict__ gam,
                const float* __restrict__ bet, short* __restrict__ z)
{
  const int t = blockIdx.x * 4 + (threadIdx.x >> 6);
  const int lane = threadIdx.x & 63;
  bf16x4_t raw = *(const bf16x4_t*)(xw + (size_t)t * 256 + lane * 4);
  float v[4];
#pragma unroll
  for (int j = 0; j < 4; j++) v[j] = b2f(raw[j]);
  float sum = v[0] + v[1] + v[2] + v[3];
  float sq  = v[0]*v[0] + v[1]*v[1] + v[2]*v[2] + v[3]*v[3];
#pragma unroll
  for (int off = 32; off > 0; off >>= 1) {
    sum += __shfl_xor(sum, off, 64);
    sq  += __shfl_xor(sq,  off, 64);
  }
  float mu = sum * (1.0f / 256.0f);
  float var = sq * (1.0f / 256.0f) - mu * mu;
  float rs = rsqrtf(var + EPS_);
  bf16x4_t o;
#pragma unroll
  for (int j = 0; j < 4; j++) {
    int c = lane * 4 + j;
    o[j] = f2b((v[j] - mu) * rs * gam[c] + bet[c]);
  }
  *(bf16x4_t*)(z + (size_t)t * 256 + lane * 4) = o;
}

// ---------------------------------------------------------------------------
// egress: token-major bf16 -> BCHW f32 out
// ---------------------------------------------------------------------------
__global__ __launch_bounds__(256)
void egress_kernel(const short* __restrict__ outtok, float* __restrict__ out)
{
  const int h = blockIdx.x % 56, b = blockIdx.x / 56;
  const int w = threadIdx.x & 63, cblk = threadIdx.x >> 6;
  const bool act = w < 56;
  const int wcl = act ? w : 55;
  const int tok = b * HW_ + ((h / 7) * 8 + wcl / 7) * P_ + (h % 7) * 7 + (wcl % 7);
  const short* src = outtok + (size_t)tok * 256 + cblk * 64;
  float* dst = out + ((size_t)b * 256 + cblk * 64) * HW_ + h * 56 + w;
#pragma unroll
  for (int j0 = 0; j0 < 64; j0 += 8) {
    bf16x8 r = *(const bf16x8*)(src + j0);
#pragma unroll
    for (int jj = 0; jj < 8; jj++)
      if (act) dst[(size_t)(j0 + jj) * HW_] = b2f(r[jj]);
  }
}

// ---------------------------------------------------------------------------
// attention (MFMA): one wave per (window, head)
// ---------------------------------------------------------------------------
__global__ __launch_bounds__(64)
void attn_kernel(const short* __restrict__ qkv, const short* __restrict__ bt,
                 short* __restrict__ out)
{
  __shared__ short Pbuf[64 * 72];
  const int bid = blockIdx.x;
  const int h = bid & 7;
  const int t0 = (bid >> 3) * P_;
  const int lane = threadIdx.x;
  const int g = lane >> 4, q = lane & 15;

  const short* qb = qkv + (size_t)t0 * 768 + h * 32;

  bf16x8 vf[2][2];
#pragma unroll
  for (int kkt = 0; kkt < 2; kkt++)
#pragma unroll
    for (int n2 = 0; n2 < 2; n2++)
#pragma unroll
      for (int jj = 0; jj < 8; jj++) {
        int key = kkt * 32 + 8 * g + jj; key = key > 48 ? 48 : key;
        vf[kkt][n2][jj] = qb[(size_t)key * 768 + 512 + n2 * 16 + q];
      }

  bf16x8 kf[4], qf[4];
#pragma unroll
  for (int mi = 0; mi < 4; mi++) {
    int r_ = mi * 16 + q; r_ = r_ > 48 ? 48 : r_;
    kf[mi] = *(const bf16x8*)(qb + (size_t)r_ * 768 + 256 + 8 * g);
  }
#pragma unroll
  for (int ni = 0; ni < 4; ni++) {
    int r_ = ni * 16 + q; r_ = r_ > 48 ? 48 : r_;
    qf[ni] = *(const bf16x8*)(qb + (size_t)r_ * 768 + 8 * g);
  }

  f32x4 sacc[4][4] = {};
#pragma unroll
  for (int mi = 0; mi < 4; mi++)
#pragma unroll
    for (int ni = 0; ni < 4; ni++)
      sacc[mi][ni] = __builtin_amdgcn_mfma_f32_16x16x32_bf16(kf[mi], qf[ni], sacc[mi][ni], 0, 0, 0);

  float mx[4] = {-1e30f, -1e30f, -1e30f, -1e30f};
  const short* btb = bt + (size_t)(h * 64) * 64 + q * 4;
#pragma unroll
  for (int mi = 0; mi < 4; mi++)
#pragma unroll
    for (int r = 0; r < 4; r++) {
      int key = mi * 16 + 4 * g + r;
      bf16x4_t bv = *(const bf16x4_t*)(btb + key * 64);
      bool valid = key < P_;
#pragma unroll
      for (int ni = 0; ni < 4; ni++) {
        float s = valid ? fmaf(sacc[mi][ni][r], SCALE_, b2f(bv[ni])) : -1e30f;
        sacc[mi][ni][r] = s;
        mx[ni] = fmaxf(mx[ni], s);
      }
    }
#pragma unroll
  for (int ni = 0; ni < 4; ni++) {
    mx[ni] = fmaxf(mx[ni], __shfl_xor(mx[ni], 16, 64));
    mx[ni] = fmaxf(mx[ni], __shfl_xor(mx[ni], 32, 64));
  }
  float sm[4] = {0.f, 0.f, 0.f, 0.f};
#pragma unroll
  for (int mi = 0; mi < 4; mi++)
#pragma unroll
    for (int ni = 0; ni < 4; ni++)
#pragma unroll
      for (int r = 0; r < 4; r++) {
        float p = __expf(sacc[mi][ni][r] - mx[ni]);
        sacc[mi][ni][r] = p;
        sm[ni] += p;
      }
#pragma unroll
  for (int ni = 0; ni < 4; ni++) {
    sm[ni] += __shfl_xor(sm[ni], 16, 64);
    sm[ni] += __shfl_xor(sm[ni], 32, 64);
    sm[ni] = 1.0f / sm[ni];
  }
#pragma unroll
  for (int ni = 0; ni < 4; ni++)
#pragma unroll
    for (int mi = 0; mi < 4; mi++) {
      bf16x4_t pv;
#pragma unroll
      for (int r = 0; r < 4; r++) pv[r] = f2b(sacc[mi][ni][r] * sm[ni]);
      *(bf16x4_t*)&Pbuf[(ni * 16 + q) * 72 + mi * 16 + 4 * g] = pv;
    }
  __syncthreads();

  f32x4 oacc[4][2] = {};
#pragma unroll
  for (int kkt = 0; kkt < 2; kkt++) {
    bf16x8 paf[4];
#pragma unroll
    for (int qi = 0; qi < 4; qi++)
      paf[qi] = *(const bf16x8*)&Pbuf[(qi * 16 + q) * 72 + kkt * 32 + 8 * g];
#pragma unroll
    for (int qi = 0; qi < 4; qi++)
#pragma unroll
      for (int n2 = 0; n2 < 2; n2++)
        oacc[qi][n2] = __builtin_amdgcn_mfma_f32_16x16x32_bf16(paf[qi], vf[kkt][n2], oacc[qi][n2], 0, 0, 0);
  }

  short* ob = out + (size_t)t0 * 256 + h * 32;
#pragma unroll
  for (int qi = 0; qi < 4; qi++)
#pragma unroll
    for (int r = 0; r < 4; r++) {
      int query = qi * 16 + 4 * g + r;
      if (query < P_) {
#pragma unroll
        for (int n2 = 0; n2 < 2; n2++)
          ob[(size_t)query * 256 + n2 * 16 + q] = f2b(oacc[qi][n2][r]);
      }
    }
}

// ---------------------------------------------------------------------------
// GEMM (R11 structure, unchanged): BM=128, BN=64*WN, threads=128*WN.
// Depth-2 LDS pipeline, raw s_barrier + counted s_waitcnt vmcnt(NLOADS).
// T2 source swizzle + swizzled ds_read.
// EPI 0: bf16 store   EPI 1: gelu(erff) -> bf16   EPI 2: in-place residual add
// ---------------------------------------------------------------------------
template<int EPI, int WN>
__global__ __launch_bounds__(128 * WN)
void gemm_kernel(const bf16* __restrict__ A, const bf16* __restrict__ Wt,
                 const float* __restrict__ bias, int N, int K,
                 bf16* __restrict__ outb, short* __restrict__ res_io)
{
  constexpr int THREADS = 128 * WN;
  constexpr int BN = 64 * WN;
  constexpr int RPP = THREADS / 4;      // rows staged per pass
  constexpr int APASS = 128 / RPP;      // 1 (WN=4) or 2 (WN=2)
  constexpr int BPASS = BN / RPP;       // 2
  constexpr int NLOADS = APASS + BPASS; // 3 (WN=4) or 4 (WN=2)
  __shared__ __align__(16) bf16 As[2][128 * 32];
  __shared__ __align__(16) bf16 Bs[2][BN * 32];

  const int tid = threadIdx.x;
  const int lane = tid & 63;
  const int wave = tid >> 6;
  const int wr = wave / WN, wc = wave % WN;
  const int bm = blockIdx.y * 128, bn = blockIdx.x * BN;

  f32x4 acc[4][4] = {};

  const int trow = tid >> 2;
  const int tcol = ((tid & 3) ^ ((tid >> 3) & 3)) * 8;   // swizzled source chunk
  const bf16* aA[APASS];
#pragma unroll
  for (int p = 0; p < APASS; p++)
    aA[p] = A + (size_t)(bm + p * RPP + trow) * K + tcol;
  const bf16* aB[BPASS];
#pragma unroll
  for (int p = 0; p < BPASS; p++)
    aB[p] = Wt + (size_t)(bn + p * RPP + trow) * K + tcol;
  const int dOff = tid * 8;

  const int kc_sw = ((lane >> 4) ^ ((lane >> 1) & 3)) * 8;  // swizzled read chunk
  const int l15 = lane & 15, g = lane >> 4;
  const int rA = wr * 64 + l15;
  const int rB = wc * 64 + l15;

  const int nt = K >> 5;

  // prologue: stage tiles 0 and 1
#pragma unroll
  for (int p = 0; p < APASS; p++) gload16(aA[p], &As[0][p * RPP * 32 + dOff]);
#pragma unroll
  for (int p = 0; p < BPASS; p++) gload16(aB[p], &Bs[0][p * RPP * 32 + dOff]);
#pragma unroll
  for (int p = 0; p < APASS; p++) gload16(aA[p] + 32, &As[1][p * RPP * 32 + dOff]);
#pragma unroll
  for (int p = 0; p < BPASS; p++) gload16(aB[p] + 32, &Bs[1][p * RPP * 32 + dOff]);

  for (int t = 0; t < nt; ++t) {
    const int cur = t & 1;
    // wait for THIS tile's stage only; next tile's loads stay in flight
    if (t + 1 < nt) {
      if constexpr (NLOADS == 3) asm volatile("s_waitcnt vmcnt(3)" ::: "memory");
      else                       asm volatile("s_waitcnt vmcnt(4)" ::: "memory");
    } else {
      asm volatile("s_waitcnt vmcnt(0)" ::: "memory");
    }
    __builtin_amdgcn_s_barrier();          // tile t visible to all waves

    bf16x8 af[4], bfr[4];
#pragma unroll
    for (int i = 0; i < 4; i++) {
      af[i]  = *(const bf16x8*)(&As[cur][(rA + i * 16) * 32 + kc_sw]);
      bfr[i] = *(const bf16x8*)(&Bs[cur][(rB + i * 16) * 32 + kc_sw]);
    }
#pragma unroll
    for (int mi = 0; mi < 4; mi++)
#pragma unroll
      for (int ni = 0; ni < 4; ni++)
        acc[mi][ni] = __builtin_amdgcn_mfma_f32_16x16x32_bf16(af[mi], bfr[ni], acc[mi][ni], 0, 0, 0);

    __builtin_amdgcn_s_barrier();          // all waves done reading buf[cur]
    if (t + 2 < nt) {                      // refill the freed buffer
      const int k2 = (t + 2) << 5;
#pragma unroll
      for (int p = 0; p < APASS; p++) gload16(aA[p] + k2, &As[cur][p * RPP * 32 + dOff]);
#pragma unroll
      for (int p = 0; p < BPASS; p++) gload16(aB[p] + k2, &Bs[cur][p * RPP * 32 + dOff]);
    }
  }

#pragma unroll
  for (int mi = 0; mi < 4; mi++) {
#pragma unroll
    for (int ni = 0; ni < 4; ni++) {
#pragma unroll
      for (int r = 0; r < 4; r++) {
        const int row = bm + wr * 64 + mi * 16 + g * 4 + r;
        const int col = bn + wc * 64 + ni * 16 + l15;
        float v = acc[mi][ni][r] + bias[col];
        if (EPI == 0) {
          outb[(size_t)row * N + col] = __float2bfloat16(v);
        } else if (EPI == 1) {
          float gv = 0.5f * v * (1.0f + erff(v * 0.70710678118f));
          outb[(size_t)row * N + col] = __float2bfloat16(gv);
        } else {
          size_t o = (size_t)row * 256 + col;
          res_io[o] = f2b(v + b2f(res_io[o]));
        }
      }
    }
  }
}

// ---------------------------------------------------------------------------
extern "C" void kernel_launch(void* const* d_in, const int* in_sizes, int n_in,
                              void* d_out, int out_size, void* d_ws, size_t ws_size,
                              hipStream_t stream)
{
  const float* x      = (const float*)d_in[0];
  const float* ln1_g  = (const float*)d_in[1];
  const float* ln1_b  = (const float*)d_in[2];
  const float* wqkv   = (const float*)d_in[3];
  const float* bqkv   = (const float*)d_in[4];
  const float* wmerge = (const float*)d_in[5];
  const float* bmerge = (const float*)d_in[6];
  const float* btab   = (const float*)d_in[7];
  const float* ln2_g  = (const float*)d_in[8];
  const float* ln2_b  = (const float*)d_in[9];
  const float* w1     = (const float*)d_in[10];
  const float* b1     = (const float*)d_in[11];
  const float* w2     = (const float*)d_in[12];
  const float* b2     = (const float*)d_in[13];
  const int*   relidx = (const int*)d_in[14];
  float* out = (float*)d_out;

  char* ws = (char*)d_ws;
  bf16*  wqkvT   = (bf16*)(ws);                   // 393,216
  bf16*  wmergeT = (bf16*)(ws + 393216);          // 131,072
  bf16*  w1T     = (bf16*)(ws + 524288);          // 524,288
  bf16*  w2T     = (bf16*)(ws + 1048576);         // 524,288
  short* battn   = (short*)(ws + 1572864);        // 65,536
  short* R1      = (short*)(ws + 1638400);        // 25,690,112 residual stream
  short* R2      = (short*)(ws + 27328512);       // 25,690,112 y -> z
  // chunked region at 53,018,624:
  //   nchunk=1: qkvc 77.1MB + attnc 25.7MB -> needs 155.8MB total (R13 proved fit)
  //   nchunk=2: qkvc 38.5MB + attnc 12.8MB (R11 fallback, 104.4MB)
  const size_t CH1_NEED = 53018624ull + (size_t)NTOK * 768 * 2 + (size_t)NTOK * 256 * 2;
  const int nchunk = (ws_size >= CH1_NEED) ? 1 : 2;
  const int ctok = NTOK / nchunk;
  short* qkvc  = (short*)(ws + 53018624);
  short* attnc = qkvc + (size_t)ctok * 768;
  short* hbuf  = qkvc;                            // aliases qkvc+attnc (dead by MLP)

  prep_kernel<<<3200, 256, 0, stream>>>(wqkv, wmerge, w1, w2, btab, relidx,
                                        wqkvT, wmergeT, w1T, w2T, battn);

  ingest_kernel<<<896, 256, 0, stream>>>(x, ln1_g, ln1_b, R1, R2);

  // attention path, nchunk window-aligned chunks (R11 GEMM shapes, bigger grids)
  for (int c = 0; c < nchunk; ++c) {
    size_t r0 = (size_t)c * ctok;
    gemm_kernel<0, 4><<<dim3(3, ctok / 128), 512, 0, stream>>>(
        (const bf16*)(R2 + r0 * 256), wqkvT, bqkv, 768, 256, (bf16*)qkvc, nullptr);
    attn_kernel<<<(ctok / P_) * 8, 64, 0, stream>>>(qkvc, battn, attnc);
    gemm_kernel<2, 2><<<dim3(2, ctok / 128), 256, 0, stream>>>(
        (const bf16*)attnc, wmergeT, bmerge, 256, 256, nullptr, R1 + r0 * 256);
  }

  // LN2 over full xw -> z
  ln2_kernel<<<NTOK / 4, 256, 0, stream>>>(R1, ln2_g, ln2_b, R2);

  // MLP, nchunk chunks
  for (int c = 0; c < nchunk; ++c) {
    size_t r0 = (size_t)c * ctok;
    gemm_kernel<1, 4><<<dim3(4, ctok / 128), 512, 0, stream>>>(
        (const bf16*)(R2 + r0 * 256), w1T, b1, 1024, 256, (bf16*)hbuf, nullptr);
    gemm_kernel<2, 2><<<dim3(2, ctok / 128), 256, 0, stream>>>(
        (const bf16*)hbuf, w2T, b2, 256, 1024, nullptr, R1 + r0 * 256);
  }

  egress_kernel<<<896, 256, 0, stream>>>(R1, out);
}